// Round 2
// 695.629 us; speedup vs baseline: 1.1282x; 1.1282x over previous
//
#include <hip/hip_runtime.h>
#include <hip/hip_bf16.h>
#include <stdint.h>

#define B_SZ 16384
#define H_SZ 1024
#define OUT_SZ 128

typedef __attribute__((ext_vector_type(4))) float f32x4;
typedef __attribute__((ext_vector_type(8))) _Float16 h16x8;
typedef unsigned short u16;
typedef unsigned int u32;

__device__ __forceinline__ u16 f2h(float f) {
  union { _Float16 h; u16 u; } v; v.h = (_Float16)f; return v.u;
}
__device__ __forceinline__ float h2f(u16 u) {
  union { u16 u; _Float16 h; } v; v.u = u; return (float)v.h;
}
__device__ __forceinline__ u32 pk2(float a, float b) {
  return (u32)f2h(a) | ((u32)f2h(b) << 16);
}

__device__ __forceinline__ void gl_lds16(const void* g, void* l) {
  __builtin_amdgcn_global_load_lds(
      (const __attribute__((address_space(1))) u32*)g,
      (__attribute__((address_space(3))) u32*)l, 16, 0, 0);
}

// ---------------------------------------------------------------------------
// NT GEMM: C[m,n] = sum_k A[m,k] * B[n,k], fp16 in, fp32 MFMA accum.
// BM=BN=128, BK=32, 256 threads (4 waves, 64x64 each via 4x4 mfma 16x16x32).
// 2-phase double-buffered staging: issue global_load_lds for tile k+1 into
// buf^1 BEFORE computing tile k; single __syncthreads() (vmcnt(0) drain) per
// k-step overlaps load latency with ds_read+MFMA.
// LDS: 2 x (8KiB A + 8KiB B) = 32 KiB -> 4 blocks/CU at launch_bounds(256,4).
// MODE 0: store fp16 C -> ep_b (AT prep)
// MODE 1: A = Z (4 stacked [B,H]; row m -> token m&3, batch m>>2);
//         epilogue: partial logits (R[t,n]+ak[n])*z_fp32[s,n] -> private
//         slot ep_f[b][t*4+s][yg]  (yg = blockIdx.y*2 + wave-half; NO atomics)
// MODE 2: v = acc + 4*ep_v[n]; fp32 -> ep_f, fp16 -> ep_b
// MODE 3: ep_f[m*N+n] = acc + ep_v[n]   (fc logits)
// ---------------------------------------------------------------------------
template<int MODE>
__global__ __launch_bounds__(256, 4) void gemm_nt(
    const u16* __restrict__ Aptr, const u16* __restrict__ Bptr,
    int N, int K,
    float* __restrict__ ep_f, u16* __restrict__ ep_b,
    const float* __restrict__ ep_v,
    const float* zf0, const float* zf1, const float* zf2, const float* zf3)
{
  constexpr int BM = 128, BN = 128, BK = 32;
  __shared__ __align__(16) u16 sA[2][BM * BK];
  __shared__ __align__(16) u16 sB[2][BN * BK];
  const int tid  = threadIdx.x;
  const int wave = tid >> 6;
  const int lane = tid & 63;
  const int qd   = lane >> 4;
  const int c16  = lane & 15;
  const int bm0  = blockIdx.x * BM;
  const int bn0  = blockIdx.y * BN;
  const int wm   = (wave >> 1) * 64;
  const int wn   = (wave & 1) * 64;
  const size_t FBS = (size_t)B_SZ * H_SZ;

  // stage one BKx(BM|BN) tile pair into buffer `buf`:
  // 512 x 16B chunks per tile; LDS slot s holds global chunk
  // c = (s&3) ^ ((row>>1)&3) of row s>>2 (XOR swizzle keeps the
  // global_load_lds wave-contiguous while making frag reads <=2-way).
  auto stage = [&](int buf, int k0) {
#pragma unroll
    for (int i = 0; i < 2; ++i) {
      int slot = tid + i * 256;
      int r = slot >> 2, pp = slot & 3;
      int cc = pp ^ ((r >> 1) & 3);
      {
        int gm = bm0 + r;
        const u16* gp;
        if (MODE == 1)
          gp = Aptr + (size_t)(gm & 3) * FBS + (size_t)(gm >> 2) * H_SZ + (k0 + cc * 8);
        else
          gp = Aptr + (size_t)gm * K + (k0 + cc * 8);
        gl_lds16(gp, &sA[buf][(size_t)(slot & ~63) * 8]);
      }
      {
        int gn = bn0 + r;
        const u16* gp = Bptr + (size_t)gn * K + (k0 + cc * 8);
        gl_lds16(gp, &sB[buf][(size_t)(slot & ~63) * 8]);
      }
    }
  };

  f32x4 acc[4][4];
#pragma unroll
  for (int i = 0; i < 4; ++i)
#pragma unroll
    for (int j = 0; j < 4; ++j)
      acc[i][j] = (f32x4){0.f, 0.f, 0.f, 0.f};

  stage(0, 0);
  __syncthreads();   // compiler emits s_waitcnt vmcnt(0) before s_barrier
  int cur = 0;
  for (int k0 = 0; k0 < K; k0 += BK) {
    if (k0 + BK < K) stage(cur ^ 1, k0 + BK);   // prefetch next tile
    h16x8 af[4], bfr[4];
#pragma unroll
    for (int im = 0; im < 4; ++im) {
      int m = wm + im * 16 + c16;
      int slot = m * 4 + (qd ^ ((m >> 1) & 3));
      af[im] = *(const h16x8*)&sA[cur][slot * 8];
    }
#pragma unroll
    for (int in = 0; in < 4; ++in) {
      int n = wn + in * 16 + c16;
      int slot = n * 4 + (qd ^ ((n >> 1) & 3));
      bfr[in] = *(const h16x8*)&sB[cur][slot * 8];
    }
#pragma unroll
    for (int im = 0; im < 4; ++im)
#pragma unroll
      for (int in = 0; in < 4; ++in)
        acc[im][in] = __builtin_amdgcn_mfma_f32_16x16x32_f16(af[im], bfr[in], acc[im][in], 0, 0, 0);
    __syncthreads();   // drains vmcnt(0): prefetched buffer complete, read buffer reusable
    cur ^= 1;
  }

  if constexpr (MODE == 0) {
#pragma unroll
    for (int im = 0; im < 4; ++im)
#pragma unroll
      for (int in = 0; in < 4; ++in) {
        int n = bn0 + wn + in * 16 + c16;
#pragma unroll
        for (int r = 0; r < 4; ++r) {
          int m = bm0 + wm + im * 16 + qd * 4 + r;
          ep_b[(size_t)m * N + n] = f2h(acc[im][in][r]);
        }
      }
  } else if constexpr (MODE == 1) {
    // acc row m = bm0+wm+im*16+qd*4+r -> batch b = m>>2, token t = r.
    // partial logit[b,t,s] over this block's 64 cols per wave:
    //   sum_n (R[t,n] + ak[n]) * z_fp32[s][b,n]
    // Written to a PRIVATE slot (no atomics, no cross-XCD line ping-pong):
    //   ep_f[(b*16 + t*4+s)*16 + yg],  yg = blockIdx.y*2 + (wn>>6)  (16 slots)
    const float* zf[4] = {zf0, zf1, zf2, zf3};
    const int yg = (int)blockIdx.y * 2 + (wn >> 6);
#pragma unroll
    for (int im = 0; im < 4; ++im) {
      int mrow = bm0 + wm + im * 16 + qd * 4;
      size_t b = (size_t)(mrow >> 2);
      float p[4][4];
#pragma unroll
      for (int r = 0; r < 4; ++r)
#pragma unroll
        for (int s = 0; s < 4; ++s) p[r][s] = 0.f;
#pragma unroll
      for (int in = 0; in < 4; ++in) {
        int n = bn0 + wn + in * 16 + c16;
        float akv = ep_v[n];
        float rv[4];
#pragma unroll
        for (int r = 0; r < 4; ++r) rv[r] = acc[im][in][r] + akv;
#pragma unroll
        for (int s = 0; s < 4; ++s) {
          float zv = zf[s][b * H_SZ + n];
#pragma unroll
          for (int r = 0; r < 4; ++r) p[r][s] += rv[r] * zv;
        }
      }
#pragma unroll
      for (int r = 0; r < 4; ++r)
#pragma unroll
        for (int s = 0; s < 4; ++s) {
          float v = p[r][s];
          v += __shfl_xor(v, 1);
          v += __shfl_xor(v, 2);
          v += __shfl_xor(v, 4);
          v += __shfl_xor(v, 8);
          if (c16 == 0) ep_f[(b * 16 + (size_t)(r * 4 + s)) * 16 + yg] = v;
        }
    }
  } else if constexpr (MODE == 2) {
#pragma unroll
    for (int im = 0; im < 4; ++im)
#pragma unroll
      for (int in = 0; in < 4; ++in) {
        int n = bn0 + wn + in * 16 + c16;
        float bvv = 4.0f * ep_v[n];
#pragma unroll
        for (int r = 0; r < 4; ++r) {
          int m = bm0 + wm + im * 16 + qd * 4 + r;
          float v = acc[im][in][r] + bvv;
          ep_f[(size_t)m * H_SZ + n] = v;
          ep_b[(size_t)m * H_SZ + n] = f2h(v);
        }
      }
  } else {
#pragma unroll
    for (int im = 0; im < 4; ++im)
#pragma unroll
      for (int in = 0; in < 4; ++in) {
        int n = bn0 + wn + in * 16 + c16;
        float bc = ep_v[n];
#pragma unroll
        for (int r = 0; r < 4; ++r) {
          int m = bm0 + wm + im * 16 + qd * 4 + r;
          ep_f[(size_t)m * N + n] = acc[im][in][r] + bc;
        }
      }
  }
}

// ---------------------------------------------------------------------------
// prep_weights: [0,1024) Wq->fp16; [1024,2048) Wk->fp16;
// [2048,3072) WvT fp16 transpose; [3072,3200) WfcT fp16 transpose;
// [3200,3456) ak[h] = sum_i Wk[h,i]*bq[i]  (fp32)
// ---------------------------------------------------------------------------
__global__ __launch_bounds__(256) void prep_weights(
    const float* __restrict__ Wq, const float* __restrict__ Wk,
    const float* __restrict__ Wv, const float* __restrict__ Wfc,
    const float* __restrict__ bq,
    u16* __restrict__ Wq16, u16* __restrict__ Wk16,
    u16* __restrict__ WvT, u16* __restrict__ WfcT,
    float* __restrict__ ak)
{
  __shared__ float t[32][33];
  int blk = blockIdx.x, tid = threadIdx.x;
  if (blk < 2048) {
    const float* src = (blk < 1024) ? Wq : Wk;
    u16* dst = (blk < 1024) ? Wq16 : Wk16;
    size_t i0 = (size_t)(blk & 1023) * 1024 + tid * 4;
    float4 v = *(const float4*)(src + i0);
    *(uint2*)(dst + i0) = make_uint2(pk2(v.x, v.y), pk2(v.z, v.w));
  } else if (blk < 3200) {
    int lx = tid & 31, ly = tid >> 5;
    if (blk < 3072) {
      int ti = blk - 2048;
      int tx = ti & 31, ty = ti >> 5;
#pragma unroll
      for (int k = 0; k < 4; ++k)
        t[ly + 8 * k][lx] = Wv[(size_t)(ty * 32 + ly + 8 * k) * 1024 + tx * 32 + lx];
      __syncthreads();
#pragma unroll
      for (int k = 0; k < 4; ++k)
        WvT[(size_t)(tx * 32 + ly + 8 * k) * 1024 + ty * 32 + lx] = f2h(t[lx][ly + 8 * k]);
    } else {
      int ti = blk - 3072;
      int tx = ti & 3, ty = ti >> 2;
#pragma unroll
      for (int k = 0; k < 4; ++k)
        t[ly + 8 * k][lx] = Wfc[(size_t)(ty * 32 + ly + 8 * k) * 128 + tx * 32 + lx];
      __syncthreads();
#pragma unroll
      for (int k = 0; k < 4; ++k)
        WfcT[(size_t)(tx * 32 + ly + 8 * k) * 1024 + ty * 32 + lx] = f2h(t[lx][ly + 8 * k]);
    }
  } else {
    int wave = tid >> 6, lane = tid & 63;
    int row = (blk - 3200) * 4 + wave;
    float s = 0.f;
    for (int i = lane; i < 1024; i += 64)
      s += Wk[(size_t)row * 1024 + i] * bq[i];
#pragma unroll
    for (int m = 1; m < 64; m <<= 1) s += __shfl_xor(s, m);
    if (lane == 0) ak[row] = s;
  }
}

__global__ __launch_bounds__(256) void convert4(
    const float* __restrict__ f1, const float* __restrict__ f2,
    const float* __restrict__ f3, const float* __restrict__ f4,
    u16* __restrict__ Zh)
{
  int a = blockIdx.x >> 13;
  const float* f = (a == 0) ? f1 : (a == 1) ? f2 : (a == 2) ? f3 : f4;
  size_t off = (size_t)(blockIdx.x & 8191) * 2048 + threadIdx.x * 8;
  float4 v0 = *(const float4*)(f + off);
  float4 v1 = *(const float4*)(f + off + 4);
  *(uint4*)(Zh + (size_t)a * B_SZ * H_SZ + off) =
      make_uint4(pk2(v0.x, v0.y), pk2(v0.z, v0.w), pk2(v1.x, v1.y), pk2(v1.z, v1.w));
}

// one wave per batch: sum the 16 per-slot partial logits -> 4x4 logits,
// softmax rows, col-sums w_s, g = sum_s w_s z_s
__global__ __launch_bounds__(256) void softmax_g(
    const float* __restrict__ pl, const u16* __restrict__ Zh,
    u16* __restrict__ G)
{
  const size_t FBS = (size_t)B_SZ * H_SZ;
  int wave = threadIdx.x >> 6, lane = threadIdx.x & 63;
  size_t b = (size_t)blockIdx.x * 4 + wave;
  // pl[b][rs][yg16]: lane reads 4 of the 16 slots for rs = lane>>2
  float4 pv = *(const float4*)(pl + b * 256 + (size_t)lane * 4);
  float part = pv.x + pv.y + pv.z + pv.w;
  part += __shfl_xor(part, 1);
  part += __shfl_xor(part, 2);
  // lane group (lane>>2) now holds logit[rs]; broadcast all 16 to every lane
  float l[16];
#pragma unroll
  for (int i = 0; i < 16; ++i) l[i] = __shfl(part, i * 4);
  float w0 = 0, w1 = 0, w2 = 0, w3 = 0;
#pragma unroll
  for (int t = 0; t < 4; ++t) {
    float a0 = l[t * 4], a1 = l[t * 4 + 1], a2 = l[t * 4 + 2], a3 = l[t * 4 + 3];
    float mx = fmaxf(fmaxf(a0, a1), fmaxf(a2, a3));
    float e0 = __expf(a0 - mx), e1 = __expf(a1 - mx), e2 = __expf(a2 - mx), e3 = __expf(a3 - mx);
    float inv = 1.0f / (e0 + e1 + e2 + e3);
    w0 += e0 * inv; w1 += e1 * inv; w2 += e2 * inv; w3 += e3 * inv;
  }
#pragma unroll
  for (int ch = 0; ch < 2; ++ch) {
    size_t h0 = (size_t)lane * 8 + ch * 512;
    float g[8];
#pragma unroll
    for (int j = 0; j < 8; ++j) g[j] = 0.f;
#pragma unroll
    for (int s = 0; s < 4; ++s) {
      float ws = (s == 0) ? w0 : (s == 1) ? w1 : (s == 2) ? w2 : w3;
      uint4 zz = *(const uint4*)(Zh + (size_t)s * FBS + b * H_SZ + h0);
      u32 zs[4] = {zz.x, zz.y, zz.z, zz.w};
#pragma unroll
      for (int j = 0; j < 4; ++j) {
        g[2 * j]     += ws * h2f((u16)(zs[j] & 0xffffu));
        g[2 * j + 1] += ws * h2f((u16)(zs[j] >> 16));
      }
    }
    *(uint4*)(G + b * H_SZ + h0) =
        make_uint4(pk2(g[0], g[1]), pk2(g[2], g[3]), pk2(g[4], g[5]), pk2(g[6], g[7]));
  }
}

// one wave per row: softmax over 128 fc logits
__global__ __launch_bounds__(256) void softmax_out(
    const float* __restrict__ L2, float* __restrict__ out)
{
  int wave = threadIdx.x >> 6, lane = threadIdx.x & 63;
  size_t row = (size_t)blockIdx.x * 4 + wave;
  float2 v = *(const float2*)(L2 + row * 128 + lane * 2);
  float mx = fmaxf(v.x, v.y);
#pragma unroll
  for (int m = 1; m < 64; m <<= 1) mx = fmaxf(mx, __shfl_xor(mx, m));
  float e0 = __expf(v.x - mx), e1 = __expf(v.y - mx);
  float s = e0 + e1;
#pragma unroll
  for (int m = 1; m < 64; m <<= 1) s += __shfl_xor(s, m);
  float inv = 1.0f / s;
  *(float2*)(out + row * 128 + lane * 2) = make_float2(e0 * inv, e1 * inv);
}

extern "C" void kernel_launch(void* const* d_in, const int* in_sizes, int n_in,
                              void* d_out, int out_size, void* d_ws, size_t ws_size,
                              hipStream_t stream)
{
  const float* f1  = (const float*)d_in[0];
  const float* f2  = (const float*)d_in[1];
  const float* f3  = (const float*)d_in[2];
  const float* f4  = (const float*)d_in[3];
  const float* Wq  = (const float*)d_in[4];
  const float* bq  = (const float*)d_in[5];
  const float* Wk  = (const float*)d_in[6];
  // d_in[7] = bk: logit contribution constant over softmax axis -> dropped.
  const float* Wv  = (const float*)d_in[8];
  const float* bv  = (const float*)d_in[9];
  const float* Wfc = (const float*)d_in[10];
  const float* bfc = (const float*)d_in[11];

  float* x_out = (float*)d_out;
  float* out2  = x_out + (size_t)B_SZ * H_SZ;

  const size_t BH = (size_t)B_SZ * H_SZ;
  const size_t HH = (size_t)H_SZ * H_SZ;
  char* w = (char*)d_ws;
  u16* Zh   = (u16*)w;  w += 4 * BH * sizeof(u16);   // 128 MiB fp16 z
  u16* G    = (u16*)w;  w += BH * sizeof(u16);       // 32 MiB
  u16* Xh   = (u16*)w;  w += BH * sizeof(u16);       // 32 MiB
  u16* Wq16 = (u16*)w;  w += HH * 2;
  u16* Wk16 = (u16*)w;  w += HH * 2;
  u16* AT   = (u16*)w;  w += HH * 2;   // AT[i,h] = sum_j Wk[i,j]Wq[h,j]
  u16* WvT  = (u16*)w;  w += HH * 2;   // WvT[n,k] = Wv[k,n]
  u16* WfcT = (u16*)w;  w += (size_t)OUT_SZ * H_SZ * 2;
  float* ak  = (float*)w;  w += H_SZ * sizeof(float);
  float* fcl = (float*)w;  w += (size_t)B_SZ * OUT_SZ * sizeof(float);
  // pl (16 MiB partial logits) overlays the start of Xh: pl is produced by
  // gemm_nt<1> and fully consumed by softmax_g BEFORE gemm_nt<2> writes Xh.
  // Keeps total workspace within the previously-passing 209 MiB layout.
  float* pl  = (float*)Xh;

  prep_weights<<<3456, 256, 0, stream>>>(Wq, Wk, Wv, Wfc, bq,
      Wq16, Wk16, WvT, WfcT, ak);
  convert4<<<32768, 256, 0, stream>>>(f1, f2, f3, f4, Zh);
  // AT = Wk @ Wq^T (fp16 out)
  gemm_nt<0><<<dim3(8, 8), 256, 0, stream>>>(
      Wk16, Wq16, 1024, 1024, nullptr, AT, nullptr,
      nullptr, nullptr, nullptr, nullptr);
  // R = Z @ AT^T, fused fp32 (R+ak)·z epilogue -> partial logits pl[b][ts][yg]
  gemm_nt<1><<<dim3(512, 8), 256, 0, stream>>>(
      Zh, AT, 1024, 1024, pl, nullptr, ak, f1, f2, f3, f4);
  softmax_g<<<4096, 256, 0, stream>>>(pl, Zh, G);
  // x = G @ Wv + 4*bv  (fp32 -> d_out, fp16 -> Xh)
  gemm_nt<2><<<dim3(128, 8), 256, 0, stream>>>(
      G, WvT, 1024, 1024, x_out, Xh, bv,
      nullptr, nullptr, nullptr, nullptr);
  // fc logits = x @ Wfc + bfc
  gemm_nt<3><<<dim3(128, 1), 256, 0, stream>>>(
      Xh, WfcT, 128, 1024, fcl, nullptr, bfc,
      nullptr, nullptr, nullptr, nullptr);
  softmax_out<<<4096, 256, 0, stream>>>(fcl, out2);
}

// Round 3
// 686.015 us; speedup vs baseline: 1.1440x; 1.0140x over previous
//
#include <hip/hip_runtime.h>
#include <hip/hip_bf16.h>
#include <stdint.h>

#define B_SZ 16384
#define H_SZ 1024
#define OUT_SZ 128

typedef __attribute__((ext_vector_type(4))) float f32x4;
typedef __attribute__((ext_vector_type(8))) _Float16 h16x8;
typedef unsigned short u16;
typedef unsigned int u32;

__device__ __forceinline__ u16 f2h(float f) {
  union { _Float16 h; u16 u; } v; v.h = (_Float16)f; return v.u;
}
__device__ __forceinline__ float h2f(u16 u) {
  union { u16 u; _Float16 h; } v; v.u = u; return (float)v.h;
}
__device__ __forceinline__ u32 pk2(float a, float b) {
  return (u32)f2h(a) | ((u32)f2h(b) << 16);
}

__device__ __forceinline__ void gl_lds16(const void* g, void* l) {
  __builtin_amdgcn_global_load_lds(
      (const __attribute__((address_space(1))) u32*)g,
      (__attribute__((address_space(3))) u32*)l, 16, 0, 0);
}

// ---------------------------------------------------------------------------
// 256x256 NT GEMM: C[m,n] = sum_k A[m,k]*B[n,k], fp16 in, fp32 MFMA accum.
// BM=BN=256, BK=64, 512 threads (8 waves 2Mx4N, each 128x64 via 8x4 mfma
// 16x16x32). 2-phase double-buffered staging (same sync skeleton as the
// verified 128^2 kernel): stage(k+1) -> compute(k) -> one __syncthreads
// (vmcnt(0)+lgkmcnt(0) drain) per K-tile. LDS 2*(32K A + 32K B) = 128 KiB,
// 1 block/CU. 64 MFMA/wave per barrier; compute phase (~2k SIMD-cyc) covers
// the 1-deep prefetch latency.
// Swizzle: row r of a tile = 8 x 16B chunks; LDS pos c holds global chunk
// c ^ (r&7) (stage pre-swizzles the SOURCE; reads apply the same XOR ->
// 2-way bank aliasing = free, global_load_lds dest stays linear).
// MODE 1: A = Z (4 stacked [B,H]; row m -> token m&3, batch m>>2);
//         epilogue: partial logits (R[t,n]+ak[n])*z_fp32[s,n] -> private
//         slot ep_f[(b*16+t*4+s)*16 + yg], yg = blockIdx.y*4 + (wave&3).
// MODE 2: v = acc + 4*ep_v[n]; fp32 -> ep_f, fp16 -> ep_b
// ---------------------------------------------------------------------------
template<int MODE>
__global__ __launch_bounds__(512, 2) void gemm_nt256(
    const u16* __restrict__ Aptr, const u16* __restrict__ Bptr,
    int K,
    float* __restrict__ ep_f, u16* __restrict__ ep_b,
    const float* __restrict__ ep_v,
    const float* zf0, const float* zf1, const float* zf2, const float* zf3)
{
  constexpr int BM = 256, BN = 256, BK = 64;
  __shared__ __align__(16) u16 sA[2][BM * BK];
  __shared__ __align__(16) u16 sB[2][BN * BK];
  const int tid  = threadIdx.x;
  const int wave = tid >> 6;
  const int lane = tid & 63;
  const int qd   = lane >> 4;
  const int c16  = lane & 15;
  const int bm0  = blockIdx.x * BM;
  const int bn0  = blockIdx.y * BN;
  const int wm   = (wave >> 2) * 128;
  const int wn   = (wave & 3) * 64;
  const size_t FBS = (size_t)B_SZ * H_SZ;

  // stage one 256x64 tile pair into buffer `buf`: 2048 x 16B chunks per
  // tile, 4 per thread; LDS pos c of row r holds global chunk c^(r&7).
  auto stage = [&](int buf, int k0) {
#pragma unroll
    for (int i = 0; i < 4; ++i) {
      int slot = tid + i * 512;
      int r = slot >> 3, c = slot & 7;
      int cc = c ^ (r & 7);
      {
        int gm = bm0 + r;
        const u16* gp;
        if (MODE == 1)
          gp = Aptr + (size_t)(gm & 3) * FBS + (size_t)(gm >> 2) * H_SZ + (k0 + cc * 8);
        else
          gp = Aptr + (size_t)gm * K + (k0 + cc * 8);
        gl_lds16(gp, &sA[buf][(size_t)(slot & ~63) * 8]);
      }
      {
        int gn = bn0 + r;
        const u16* gp = Bptr + (size_t)gn * K + (k0 + cc * 8);
        gl_lds16(gp, &sB[buf][(size_t)(slot & ~63) * 8]);
      }
    }
  };

  f32x4 acc[8][4];
#pragma unroll
  for (int i = 0; i < 8; ++i)
#pragma unroll
    for (int j = 0; j < 4; ++j)
      acc[i][j] = (f32x4){0.f, 0.f, 0.f, 0.f};

  stage(0, 0);
  __syncthreads();
  int cur = 0;
  for (int k0 = 0; k0 < K; k0 += BK) {
    if (k0 + BK < K) stage(cur ^ 1, k0 + BK);   // prefetch next K-tile
#pragma unroll
    for (int ks = 0; ks < 2; ++ks) {            // two 32-wide k-steps
      h16x8 af[8], bfr[4];
#pragma unroll
      for (int im = 0; im < 8; ++im) {
        int m = wm + im * 16 + c16;
        af[im] = *(const h16x8*)&sA[cur][m * 64 + (((ks * 4 + qd) ^ (m & 7)) * 8)];
      }
#pragma unroll
      for (int in = 0; in < 4; ++in) {
        int n = wn + in * 16 + c16;
        bfr[in] = *(const h16x8*)&sB[cur][n * 64 + (((ks * 4 + qd) ^ (n & 7)) * 8)];
      }
#pragma unroll
      for (int im = 0; im < 8; ++im)
#pragma unroll
        for (int in = 0; in < 4; ++in)
          acc[im][in] = __builtin_amdgcn_mfma_f32_16x16x32_f16(af[im], bfr[in], acc[im][in], 0, 0, 0);
    }
    __syncthreads();   // drains vmcnt(0): prefetched buffer complete, read buffer reusable
    cur ^= 1;
  }

  if constexpr (MODE == 1) {
    // acc row m = bm0+wm+im*16+qd*4+r -> batch b = m>>2, token t = r.
    // partial logit[b,t,s] over this block's 64 cols per wave:
    //   sum_n (R[t,n] + ak[n]) * z_fp32[s][b,n]
    // -> private slot ep_f[(b*16 + t*4+s)*16 + yg], yg = by*4 + (wave&3).
    const float* zf[4] = {zf0, zf1, zf2, zf3};
    const int yg = (int)blockIdx.y * 4 + (wave & 3);
#pragma unroll
    for (int im = 0; im < 8; ++im) {
      int mrow = bm0 + wm + im * 16 + qd * 4;
      size_t b = (size_t)(mrow >> 2);
      float p[4][4];
#pragma unroll
      for (int r = 0; r < 4; ++r)
#pragma unroll
        for (int s = 0; s < 4; ++s) p[r][s] = 0.f;
#pragma unroll
      for (int in = 0; in < 4; ++in) {
        int n = bn0 + wn + in * 16 + c16;
        float akv = ep_v[n];
        float rv[4];
#pragma unroll
        for (int r = 0; r < 4; ++r) rv[r] = acc[im][in][r] + akv;
#pragma unroll
        for (int s = 0; s < 4; ++s) {
          float zv = zf[s][b * H_SZ + n];
#pragma unroll
          for (int r = 0; r < 4; ++r) p[r][s] += rv[r] * zv;
        }
      }
#pragma unroll
      for (int r = 0; r < 4; ++r)
#pragma unroll
        for (int s = 0; s < 4; ++s) {
          float v = p[r][s];
          v += __shfl_xor(v, 1);
          v += __shfl_xor(v, 2);
          v += __shfl_xor(v, 4);
          v += __shfl_xor(v, 8);
          if (c16 == 0) ep_f[(b * 16 + (size_t)(r * 4 + s)) * 16 + yg] = v;
        }
    }
  } else {   // MODE 2
#pragma unroll
    for (int im = 0; im < 8; ++im)
#pragma unroll
      for (int in = 0; in < 4; ++in) {
        int n = bn0 + wn + in * 16 + c16;
        float bvv = 4.0f * ep_v[n];
#pragma unroll
        for (int r = 0; r < 4; ++r) {
          int m = bm0 + wm + im * 16 + qd * 4 + r;
          float v = acc[im][in][r] + bvv;
          ep_f[(size_t)m * H_SZ + n] = v;
          ep_b[(size_t)m * H_SZ + n] = f2h(v);
        }
      }
  }
}

// ---------------------------------------------------------------------------
// 128x128 NT GEMM (verified 2-phase) — kept for the small shapes:
// MODE 0: store fp16 C -> ep_b (AT prep, 1024^3)
// MODE 3: ep_f[m*N+n] = acc + ep_v[n]  (fc logits, N=128)
// ---------------------------------------------------------------------------
template<int MODE>
__global__ __launch_bounds__(256, 4) void gemm_nt(
    const u16* __restrict__ Aptr, const u16* __restrict__ Bptr,
    int N, int K,
    float* __restrict__ ep_f, u16* __restrict__ ep_b,
    const float* __restrict__ ep_v)
{
  constexpr int BM = 128, BN = 128, BK = 32;
  __shared__ __align__(16) u16 sA[2][BM * BK];
  __shared__ __align__(16) u16 sB[2][BN * BK];
  const int tid  = threadIdx.x;
  const int wave = tid >> 6;
  const int lane = tid & 63;
  const int qd   = lane >> 4;
  const int c16  = lane & 15;
  const int bm0  = blockIdx.x * BM;
  const int bn0  = blockIdx.y * BN;
  const int wm   = (wave >> 1) * 64;
  const int wn   = (wave & 1) * 64;

  auto stage = [&](int buf, int k0) {
#pragma unroll
    for (int i = 0; i < 2; ++i) {
      int slot = tid + i * 256;
      int r = slot >> 2, pp = slot & 3;
      int cc = pp ^ ((r >> 1) & 3);
      {
        int gm = bm0 + r;
        const u16* gp = Aptr + (size_t)gm * K + (k0 + cc * 8);
        gl_lds16(gp, &sA[buf][(size_t)(slot & ~63) * 8]);
      }
      {
        int gn = bn0 + r;
        const u16* gp = Bptr + (size_t)gn * K + (k0 + cc * 8);
        gl_lds16(gp, &sB[buf][(size_t)(slot & ~63) * 8]);
      }
    }
  };

  f32x4 acc[4][4];
#pragma unroll
  for (int i = 0; i < 4; ++i)
#pragma unroll
    for (int j = 0; j < 4; ++j)
      acc[i][j] = (f32x4){0.f, 0.f, 0.f, 0.f};

  stage(0, 0);
  __syncthreads();
  int cur = 0;
  for (int k0 = 0; k0 < K; k0 += BK) {
    if (k0 + BK < K) stage(cur ^ 1, k0 + BK);
    h16x8 af[4], bfr[4];
#pragma unroll
    for (int im = 0; im < 4; ++im) {
      int m = wm + im * 16 + c16;
      int slot = m * 4 + (qd ^ ((m >> 1) & 3));
      af[im] = *(const h16x8*)&sA[cur][slot * 8];
    }
#pragma unroll
    for (int in = 0; in < 4; ++in) {
      int n = wn + in * 16 + c16;
      int slot = n * 4 + (qd ^ ((n >> 1) & 3));
      bfr[in] = *(const h16x8*)&sB[cur][slot * 8];
    }
#pragma unroll
    for (int im = 0; im < 4; ++im)
#pragma unroll
      for (int in = 0; in < 4; ++in)
        acc[im][in] = __builtin_amdgcn_mfma_f32_16x16x32_f16(af[im], bfr[in], acc[im][in], 0, 0, 0);
    __syncthreads();
    cur ^= 1;
  }

  if constexpr (MODE == 0) {
#pragma unroll
    for (int im = 0; im < 4; ++im)
#pragma unroll
      for (int in = 0; in < 4; ++in) {
        int n = bn0 + wn + in * 16 + c16;
#pragma unroll
        for (int r = 0; r < 4; ++r) {
          int m = bm0 + wm + im * 16 + qd * 4 + r;
          ep_b[(size_t)m * N + n] = f2h(acc[im][in][r]);
        }
      }
  } else {
#pragma unroll
    for (int im = 0; im < 4; ++im)
#pragma unroll
      for (int in = 0; in < 4; ++in) {
        int n = bn0 + wn + in * 16 + c16;
        float bc = ep_v[n];
#pragma unroll
        for (int r = 0; r < 4; ++r) {
          int m = bm0 + wm + im * 16 + qd * 4 + r;
          ep_f[(size_t)m * N + n] = acc[im][in][r] + bc;
        }
      }
  }
}

// ---------------------------------------------------------------------------
// prep_weights: [0,1024) Wq->fp16; [1024,2048) Wk->fp16;
// [2048,3072) WvT fp16 transpose; [3072,3200) WfcT fp16 transpose;
// [3200,3456) ak[h] = sum_i Wk[h,i]*bq[i]  (fp32)
// ---------------------------------------------------------------------------
__global__ __launch_bounds__(256) void prep_weights(
    const float* __restrict__ Wq, const float* __restrict__ Wk,
    const float* __restrict__ Wv, const float* __restrict__ Wfc,
    const float* __restrict__ bq,
    u16* __restrict__ Wq16, u16* __restrict__ Wk16,
    u16* __restrict__ WvT, u16* __restrict__ WfcT,
    float* __restrict__ ak)
{
  __shared__ float t[32][33];
  int blk = blockIdx.x, tid = threadIdx.x;
  if (blk < 2048) {
    const float* src = (blk < 1024) ? Wq : Wk;
    u16* dst = (blk < 1024) ? Wq16 : Wk16;
    size_t i0 = (size_t)(blk & 1023) * 1024 + tid * 4;
    float4 v = *(const float4*)(src + i0);
    *(uint2*)(dst + i0) = make_uint2(pk2(v.x, v.y), pk2(v.z, v.w));
  } else if (blk < 3200) {
    int lx = tid & 31, ly = tid >> 5;
    if (blk < 3072) {
      int ti = blk - 2048;
      int tx = ti & 31, ty = ti >> 5;
#pragma unroll
      for (int k = 0; k < 4; ++k)
        t[ly + 8 * k][lx] = Wv[(size_t)(ty * 32 + ly + 8 * k) * 1024 + tx * 32 + lx];
      __syncthreads();
#pragma unroll
      for (int k = 0; k < 4; ++k)
        WvT[(size_t)(tx * 32 + ly + 8 * k) * 1024 + ty * 32 + lx] = f2h(t[lx][ly + 8 * k]);
    } else {
      int ti = blk - 3072;
      int tx = ti & 3, ty = ti >> 2;
#pragma unroll
      for (int k = 0; k < 4; ++k)
        t[ly + 8 * k][lx] = Wfc[(size_t)(ty * 32 + ly + 8 * k) * 128 + tx * 32 + lx];
      __syncthreads();
#pragma unroll
      for (int k = 0; k < 4; ++k)
        WfcT[(size_t)(tx * 32 + ly + 8 * k) * 1024 + ty * 32 + lx] = f2h(t[lx][ly + 8 * k]);
    }
  } else {
    int wave = tid >> 6, lane = tid & 63;
    int row = (blk - 3200) * 4 + wave;
    float s = 0.f;
    for (int i = lane; i < 1024; i += 64)
      s += Wk[(size_t)row * 1024 + i] * bq[i];
#pragma unroll
    for (int m = 1; m < 64; m <<= 1) s += __shfl_xor(s, m);
    if (lane == 0) ak[row] = s;
  }
}

__global__ __launch_bounds__(256) void convert4(
    const float* __restrict__ f1, const float* __restrict__ f2,
    const float* __restrict__ f3, const float* __restrict__ f4,
    u16* __restrict__ Zh)
{
  int a = blockIdx.x >> 13;
  const float* f = (a == 0) ? f1 : (a == 1) ? f2 : (a == 2) ? f3 : f4;
  size_t off = (size_t)(blockIdx.x & 8191) * 2048 + threadIdx.x * 8;
  float4 v0 = *(const float4*)(f + off);
  float4 v1 = *(const float4*)(f + off + 4);
  *(uint4*)(Zh + (size_t)a * B_SZ * H_SZ + off) =
      make_uint4(pk2(v0.x, v0.y), pk2(v0.z, v0.w), pk2(v1.x, v1.y), pk2(v1.z, v1.w));
}

// one wave per batch: sum the 16 per-slot partial logits -> 4x4 logits,
// softmax rows, col-sums w_s, g = sum_s w_s z_s
__global__ __launch_bounds__(256) void softmax_g(
    const float* __restrict__ pl, const u16* __restrict__ Zh,
    u16* __restrict__ G)
{
  const size_t FBS = (size_t)B_SZ * H_SZ;
  int wave = threadIdx.x >> 6, lane = threadIdx.x & 63;
  size_t b = (size_t)blockIdx.x * 4 + wave;
  // pl[b][rs][yg16]: lane reads 4 of the 16 slots for rs = lane>>2
  float4 pv = *(const float4*)(pl + b * 256 + (size_t)lane * 4);
  float part = pv.x + pv.y + pv.z + pv.w;
  part += __shfl_xor(part, 1);
  part += __shfl_xor(part, 2);
  // lane group (lane>>2) now holds logit[rs]; broadcast all 16 to every lane
  float l[16];
#pragma unroll
  for (int i = 0; i < 16; ++i) l[i] = __shfl(part, i * 4);
  float w0 = 0, w1 = 0, w2 = 0, w3 = 0;
#pragma unroll
  for (int t = 0; t < 4; ++t) {
    float a0 = l[t * 4], a1 = l[t * 4 + 1], a2 = l[t * 4 + 2], a3 = l[t * 4 + 3];
    float mx = fmaxf(fmaxf(a0, a1), fmaxf(a2, a3));
    float e0 = __expf(a0 - mx), e1 = __expf(a1 - mx), e2 = __expf(a2 - mx), e3 = __expf(a3 - mx);
    float inv = 1.0f / (e0 + e1 + e2 + e3);
    w0 += e0 * inv; w1 += e1 * inv; w2 += e2 * inv; w3 += e3 * inv;
  }
#pragma unroll
  for (int ch = 0; ch < 2; ++ch) {
    size_t h0 = (size_t)lane * 8 + ch * 512;
    float g[8];
#pragma unroll
    for (int j = 0; j < 8; ++j) g[j] = 0.f;
#pragma unroll
    for (int s = 0; s < 4; ++s) {
      float ws = (s == 0) ? w0 : (s == 1) ? w1 : (s == 2) ? w2 : w3;
      uint4 zz = *(const uint4*)(Zh + (size_t)s * FBS + b * H_SZ + h0);
      u32 zs[4] = {zz.x, zz.y, zz.z, zz.w};
#pragma unroll
      for (int j = 0; j < 4; ++j) {
        g[2 * j]     += ws * h2f((u16)(zs[j] & 0xffffu));
        g[2 * j + 1] += ws * h2f((u16)(zs[j] >> 16));
      }
    }
    *(uint4*)(G + b * H_SZ + h0) =
        make_uint4(pk2(g[0], g[1]), pk2(g[2], g[3]), pk2(g[4], g[5]), pk2(g[6], g[7]));
  }
}

// one wave per row: softmax over 128 fc logits
__global__ __launch_bounds__(256) void softmax_out(
    const float* __restrict__ L2, float* __restrict__ out)
{
  int wave = threadIdx.x >> 6, lane = threadIdx.x & 63;
  size_t row = (size_t)blockIdx.x * 4 + wave;
  float2 v = *(const float2*)(L2 + row * 128 + lane * 2);
  float mx = fmaxf(v.x, v.y);
#pragma unroll
  for (int m = 1; m < 64; m <<= 1) mx = fmaxf(mx, __shfl_xor(mx, m));
  float e0 = __expf(v.x - mx), e1 = __expf(v.y - mx);
  float s = e0 + e1;
#pragma unroll
  for (int m = 1; m < 64; m <<= 1) s += __shfl_xor(s, m);
  float inv = 1.0f / s;
  *(float2*)(out + row * 128 + lane * 2) = make_float2(e0 * inv, e1 * inv);
}

extern "C" void kernel_launch(void* const* d_in, const int* in_sizes, int n_in,
                              void* d_out, int out_size, void* d_ws, size_t ws_size,
                              hipStream_t stream)
{
  const float* f1  = (const float*)d_in[0];
  const float* f2  = (const float*)d_in[1];
  const float* f3  = (const float*)d_in[2];
  const float* f4  = (const float*)d_in[3];
  const float* Wq  = (const float*)d_in[4];
  const float* bq  = (const float*)d_in[5];
  const float* Wk  = (const float*)d_in[6];
  // d_in[7] = bk: logit contribution constant over softmax axis -> dropped.
  const float* Wv  = (const float*)d_in[8];
  const float* bv  = (const float*)d_in[9];
  const float* Wfc = (const float*)d_in[10];
  const float* bfc = (const float*)d_in[11];

  float* x_out = (float*)d_out;
  float* out2  = x_out + (size_t)B_SZ * H_SZ;

  const size_t BH = (size_t)B_SZ * H_SZ;
  const size_t HH = (size_t)H_SZ * H_SZ;
  char* w = (char*)d_ws;
  u16* Zh   = (u16*)w;  w += 4 * BH * sizeof(u16);   // 128 MiB fp16 z
  u16* G    = (u16*)w;  w += BH * sizeof(u16);       // 32 MiB
  u16* Xh   = (u16*)w;  w += BH * sizeof(u16);       // 32 MiB
  u16* Wq16 = (u16*)w;  w += HH * 2;
  u16* Wk16 = (u16*)w;  w += HH * 2;
  u16* AT   = (u16*)w;  w += HH * 2;   // AT[i,h] = sum_j Wk[i,j]Wq[h,j]
  u16* WvT  = (u16*)w;  w += HH * 2;   // WvT[n,k] = Wv[k,n]
  u16* WfcT = (u16*)w;  w += (size_t)OUT_SZ * H_SZ * 2;
  float* ak  = (float*)w;  w += H_SZ * sizeof(float);
  float* fcl = (float*)w;  w += (size_t)B_SZ * OUT_SZ * sizeof(float);
  // pl (16 MiB partial logits) overlays the start of Xh: pl is produced by
  // gemm_nt256<1> and fully consumed by softmax_g BEFORE gemm_nt256<2>
  // writes Xh. Keeps total workspace within the previously-passing layout.
  float* pl  = (float*)Xh;

  prep_weights<<<3456, 256, 0, stream>>>(Wq, Wk, Wv, Wfc, bq,
      Wq16, Wk16, WvT, WfcT, ak);
  convert4<<<32768, 256, 0, stream>>>(f1, f2, f3, f4, Zh);
  // AT = Wk @ Wq^T (fp16 out)
  gemm_nt<0><<<dim3(8, 8), 256, 0, stream>>>(
      Wk16, Wq16, 1024, 1024, nullptr, AT, nullptr);
  // R = Z @ AT^T, fused fp32 (R+ak)·z epilogue -> partial logits pl[b][ts][yg]
  gemm_nt256<1><<<dim3(256, 4), 512, 0, stream>>>(
      Zh, AT, 1024, pl, nullptr, ak, f1, f2, f3, f4);
  softmax_g<<<4096, 256, 0, stream>>>(pl, Zh, G);
  // x = G @ Wv + 4*bv  (fp32 -> d_out, fp16 -> Xh)
  gemm_nt256<2><<<dim3(64, 4), 512, 0, stream>>>(
      G, WvT, 1024, x_out, Xh, bv,
      nullptr, nullptr, nullptr, nullptr);
  // fc logits = x @ Wfc + bfc
  gemm_nt<3><<<dim3(128, 1), 256, 0, stream>>>(
      Xh, WfcT, 128, 1024, fcl, nullptr, bfc);
  softmax_out<<<4096, 256, 0, stream>>>(fcl, out2);
}

// Round 4
// 678.931 us; speedup vs baseline: 1.1560x; 1.0104x over previous
//
#include <hip/hip_runtime.h>
#include <hip/hip_bf16.h>
#include <stdint.h>

#define B_SZ 16384
#define H_SZ 1024
#define OUT_SZ 128

typedef __attribute__((ext_vector_type(4))) float f32x4;
typedef __attribute__((ext_vector_type(8))) _Float16 h16x8;
typedef unsigned short u16;
typedef unsigned int u32;

__device__ __forceinline__ u16 f2h(float f) {
  union { _Float16 h; u16 u; } v; v.h = (_Float16)f; return v.u;
}
__device__ __forceinline__ float h2f(u16 u) {
  union { u16 u; _Float16 h; } v; v.u = u; return (float)v.h;
}
__device__ __forceinline__ u32 pk2(float a, float b) {
  return (u32)f2h(a) | ((u32)f2h(b) << 16);
}

__device__ __forceinline__ void gl_lds16(const void* g, void* l) {
  __builtin_amdgcn_global_load_lds(
      (const __attribute__((address_space(1))) u32*)g,
      (__attribute__((address_space(3))) u32*)l, 16, 0, 0);
}

// ---------------------------------------------------------------------------
// 256x256 NT GEMM, K=1024: C[m,n] = sum_k A[m,k]*B[n,k], fp16 in, fp32 MFMA.
// BK=32, 4-slot LDS ring (4 x (8K A + 8K B) = 128 KiB), depth-3 prefetch with
// COUNTED vmcnt (never 0 in the main loop — T4): per tile
//   vmcnt(8)  -> oldest tile landed, 2 tiles stay in flight across barrier
//   s_barrier -> all waves' loads for tile t landed; tile t-1 fully consumed
//   stage(t+3) into slot (t+3)&3 (= slot of t-1, freed by the barrier)
//   12 ds_read_b128 -> setprio(1) 32 MFMA setprio(0)
// 512 threads (8 waves 2Mx4N, per-wave 128x64 via 8x4 mfma 16x16x32).
// Swizzle: identical to the verified 128^2/BK=32 kernel: LDS chunk position
// c of row r holds global chunk c ^ ((r>>1)&3); frag reads apply the same
// XOR -> <=2-way bank aliasing (free), global_load_lds dest stays linear.
// MODE 1: A = Z (4 stacked [B,H]; row m -> token m&3, batch m>>2);
//         epilogue: partial logits (R[t,n]+ak[n])*Zh[s,b,n] (fp16 z) ->
//         private slot ep_f[(b*16+t*4+s)*16 + yg], yg = blockIdx.y*4+(wave&3).
// MODE 2: v = acc + 4*ep_v[n]; fp32 -> ep_f, fp16 -> ep_b
// ---------------------------------------------------------------------------
template<int MODE>
__global__ __launch_bounds__(512, 2) void gemm_nt256(
    const u16* __restrict__ Aptr, const u16* __restrict__ Bptr,
    float* __restrict__ ep_f, u16* __restrict__ ep_b,
    const float* __restrict__ ep_v, const u16* __restrict__ Zep)
{
  constexpr int BM = 256, BN = 256, BK = 32, K = 1024, NT = K / BK;
  __shared__ __align__(16) u16 sA[4][BM * BK];
  __shared__ __align__(16) u16 sB[4][BN * BK];
  const int tid  = threadIdx.x;
  const int wave = tid >> 6;
  const int lane = tid & 63;
  const int qd   = lane >> 4;
  const int c16  = lane & 15;
  const int bm0  = blockIdx.x * BM;
  const int bn0  = blockIdx.y * BN;
  const int wm   = (wave >> 2) * 128;
  const int wn   = (wave & 3) * 64;
  const size_t FBS = (size_t)B_SZ * H_SZ;

  // stage one 256x32 tile pair into ring slot `buf` (1024 chunks x 16B per
  // tile, 2 per thread). Each wave-instruction writes a linear 1KiB LDS
  // span; the SOURCE is pre-swizzled (chunk cc = c ^ ((r>>1)&3)).
  auto stage = [&](int buf, int t) {
    const int k0 = t * BK;
#pragma unroll
    for (int i = 0; i < 2; ++i) {
      int slot = tid + i * 512;
      int r = slot >> 2, c = slot & 3;
      int cc = c ^ ((r >> 1) & 3);
      {
        int gm = bm0 + r;
        const u16* gp;
        if (MODE == 1)
          gp = Aptr + (size_t)(gm & 3) * FBS + (size_t)(gm >> 2) * H_SZ + (k0 + cc * 8);
        else
          gp = Aptr + (size_t)gm * K + (k0 + cc * 8);
        gl_lds16(gp, &sA[buf][(size_t)(slot & ~63) * 8]);
      }
      {
        int gn = bn0 + r;
        const u16* gp = Bptr + (size_t)gn * K + (k0 + cc * 8);
        gl_lds16(gp, &sB[buf][(size_t)(slot & ~63) * 8]);
      }
    }
  };

  f32x4 acc[8][4];
#pragma unroll
  for (int i = 0; i < 8; ++i)
#pragma unroll
    for (int j = 0; j < 4; ++j)
      acc[i][j] = (f32x4){0.f, 0.f, 0.f, 0.f};

  // depth-3 prologue: 12 VMEM ops/thread in flight
  stage(0, 0);
  stage(1, 1);
  stage(2, 2);

  for (int t = 0; t < NT; ++t) {
    const int buf = t & 3;
    // counted wait: own oldest-tile loads (4 VMEM/tile/thread) landed;
    // newer tiles stay in flight across the barrier (T4).
    if (t + 2 < NT)      asm volatile("s_waitcnt vmcnt(8)" ::: "memory");
    else if (t + 1 < NT) asm volatile("s_waitcnt vmcnt(4)" ::: "memory");
    else                 asm volatile("s_waitcnt vmcnt(0)" ::: "memory");
    __builtin_amdgcn_s_barrier();
    asm volatile("" ::: "memory");   // no LDS read hoisted above the barrier
    // slot (t+3)&3 held tile t-1, fully consumed by all waves (their MFMAs
    // precede this barrier in program order, lgkmcnt-complete).
    if (t + 3 < NT) stage((t + 3) & 3, t + 3);

    h16x8 af[8], bfr[4];
#pragma unroll
    for (int im = 0; im < 8; ++im) {
      int m = wm + im * 16 + c16;
      int slot = m * 4 + (qd ^ ((m >> 1) & 3));
      af[im] = *(const h16x8*)&sA[buf][slot * 8];
    }
#pragma unroll
    for (int in = 0; in < 4; ++in) {
      int n = wn + in * 16 + c16;
      int slot = n * 4 + (qd ^ ((n >> 1) & 3));
      bfr[in] = *(const h16x8*)&sB[buf][slot * 8];
    }
    __builtin_amdgcn_s_setprio(1);
#pragma unroll
    for (int im = 0; im < 8; ++im)
#pragma unroll
      for (int in = 0; in < 4; ++in)
        acc[im][in] = __builtin_amdgcn_mfma_f32_16x16x32_f16(af[im], bfr[in], acc[im][in], 0, 0, 0);
    __builtin_amdgcn_s_setprio(0);
  }

  if constexpr (MODE == 1) {
    // acc row m = bm0+wm+im*16+qd*4+r -> batch b = m>>2, token t = r.
    // partial logit[b,t,s] over this block's 64 cols per wave:
    //   sum_n (R[t,n] + ak[n]) * Zh[s][b,n]   (fp16 z, LLC-warm)
    // -> private slot ep_f[(b*16 + t*4+s)*16 + yg], yg = by*4 + (wave&3).
    const int yg = (int)blockIdx.y * 4 + (wave & 3);
#pragma unroll
    for (int im = 0; im < 8; ++im) {
      int mrow = bm0 + wm + im * 16 + qd * 4;
      size_t b = (size_t)(mrow >> 2);
      float p[4][4];
#pragma unroll
      for (int r = 0; r < 4; ++r)
#pragma unroll
        for (int s = 0; s < 4; ++s) p[r][s] = 0.f;
#pragma unroll
      for (int in = 0; in < 4; ++in) {
        int n = bn0 + wn + in * 16 + c16;
        float akv = ep_v[n];
        float rv[4];
#pragma unroll
        for (int r = 0; r < 4; ++r) rv[r] = acc[im][in][r] + akv;
#pragma unroll
        for (int s = 0; s < 4; ++s) {
          float zv = h2f(Zep[(size_t)s * FBS + b * H_SZ + n]);
#pragma unroll
          for (int r = 0; r < 4; ++r) p[r][s] += rv[r] * zv;
        }
      }
#pragma unroll
      for (int r = 0; r < 4; ++r)
#pragma unroll
        for (int s = 0; s < 4; ++s) {
          float v = p[r][s];
          v += __shfl_xor(v, 1);
          v += __shfl_xor(v, 2);
          v += __shfl_xor(v, 4);
          v += __shfl_xor(v, 8);
          if (c16 == 0) ep_f[(b * 16 + (size_t)(r * 4 + s)) * 16 + yg] = v;
        }
    }
  } else {   // MODE 2
#pragma unroll
    for (int im = 0; im < 8; ++im)
#pragma unroll
      for (int in = 0; in < 4; ++in) {
        int n = bn0 + wn + in * 16 + c16;
        float bvv = 4.0f * ep_v[n];
#pragma unroll
        for (int r = 0; r < 4; ++r) {
          int m = bm0 + wm + im * 16 + qd * 4 + r;
          float v = acc[im][in][r] + bvv;
          ep_f[(size_t)m * H_SZ + n] = v;
          ep_b[(size_t)m * H_SZ + n] = f2h(v);
        }
      }
  }
}

// ---------------------------------------------------------------------------
// 128x128 NT GEMM (verified 2-phase) — kept for the small shapes:
// MODE 0: store fp16 C -> ep_b (AT prep, 1024^3)
// MODE 3: ep_f[m*N+n] = acc + ep_v[n]  (fc logits, N=128)
// ---------------------------------------------------------------------------
template<int MODE>
__global__ __launch_bounds__(256, 4) void gemm_nt(
    const u16* __restrict__ Aptr, const u16* __restrict__ Bptr,
    int N, int K,
    float* __restrict__ ep_f, u16* __restrict__ ep_b,
    const float* __restrict__ ep_v)
{
  constexpr int BM = 128, BN = 128, BK = 32;
  __shared__ __align__(16) u16 sA[2][BM * BK];
  __shared__ __align__(16) u16 sB[2][BN * BK];
  const int tid  = threadIdx.x;
  const int wave = tid >> 6;
  const int lane = tid & 63;
  const int qd   = lane >> 4;
  const int c16  = lane & 15;
  const int bm0  = blockIdx.x * BM;
  const int bn0  = blockIdx.y * BN;
  const int wm   = (wave >> 1) * 64;
  const int wn   = (wave & 1) * 64;

  auto stage = [&](int buf, int k0) {
#pragma unroll
    for (int i = 0; i < 2; ++i) {
      int slot = tid + i * 256;
      int r = slot >> 2, pp = slot & 3;
      int cc = pp ^ ((r >> 1) & 3);
      {
        int gm = bm0 + r;
        const u16* gp = Aptr + (size_t)gm * K + (k0 + cc * 8);
        gl_lds16(gp, &sA[buf][(size_t)(slot & ~63) * 8]);
      }
      {
        int gn = bn0 + r;
        const u16* gp = Bptr + (size_t)gn * K + (k0 + cc * 8);
        gl_lds16(gp, &sB[buf][(size_t)(slot & ~63) * 8]);
      }
    }
  };

  f32x4 acc[4][4];
#pragma unroll
  for (int i = 0; i < 4; ++i)
#pragma unroll
    for (int j = 0; j < 4; ++j)
      acc[i][j] = (f32x4){0.f, 0.f, 0.f, 0.f};

  stage(0, 0);
  __syncthreads();
  int cur = 0;
  for (int k0 = 0; k0 < K; k0 += BK) {
    if (k0 + BK < K) stage(cur ^ 1, k0 + BK);
    h16x8 af[4], bfr[4];
#pragma unroll
    for (int im = 0; im < 4; ++im) {
      int m = wm + im * 16 + c16;
      int slot = m * 4 + (qd ^ ((m >> 1) & 3));
      af[im] = *(const h16x8*)&sA[cur][slot * 8];
    }
#pragma unroll
    for (int in = 0; in < 4; ++in) {
      int n = wn + in * 16 + c16;
      int slot = n * 4 + (qd ^ ((n >> 1) & 3));
      bfr[in] = *(const h16x8*)&sB[cur][slot * 8];
    }
#pragma unroll
    for (int im = 0; im < 4; ++im)
#pragma unroll
      for (int in = 0; in < 4; ++in)
        acc[im][in] = __builtin_amdgcn_mfma_f32_16x16x32_f16(af[im], bfr[in], acc[im][in], 0, 0, 0);
    __syncthreads();
    cur ^= 1;
  }

  if constexpr (MODE == 0) {
#pragma unroll
    for (int im = 0; im < 4; ++im)
#pragma unroll
      for (int in = 0; in < 4; ++in) {
        int n = bn0 + wn + in * 16 + c16;
#pragma unroll
        for (int r = 0; r < 4; ++r) {
          int m = bm0 + wm + im * 16 + qd * 4 + r;
          ep_b[(size_t)m * N + n] = f2h(acc[im][in][r]);
        }
      }
  } else {
#pragma unroll
    for (int im = 0; im < 4; ++im)
#pragma unroll
      for (int in = 0; in < 4; ++in) {
        int n = bn0 + wn + in * 16 + c16;
        float bc = ep_v[n];
#pragma unroll
        for (int r = 0; r < 4; ++r) {
          int m = bm0 + wm + im * 16 + qd * 4 + r;
          ep_f[(size_t)m * N + n] = acc[im][in][r] + bc;
        }
      }
  }
}

// ---------------------------------------------------------------------------
// prep_weights: [0,1024) Wq->fp16; [1024,2048) Wk->fp16;
// [2048,3072) WvT fp16 transpose; [3072,3200) WfcT fp16 transpose;
// [3200,3456) ak[h] = sum_i Wk[h,i]*bq[i]  (fp32)
// ---------------------------------------------------------------------------
__global__ __launch_bounds__(256) void prep_weights(
    const float* __restrict__ Wq, const float* __restrict__ Wk,
    const float* __restrict__ Wv, const float* __restrict__ Wfc,
    const float* __restrict__ bq,
    u16* __restrict__ Wq16, u16* __restrict__ Wk16,
    u16* __restrict__ WvT, u16* __restrict__ WfcT,
    float* __restrict__ ak)
{
  __shared__ float t[32][33];
  int blk = blockIdx.x, tid = threadIdx.x;
  if (blk < 2048) {
    const float* src = (blk < 1024) ? Wq : Wk;
    u16* dst = (blk < 1024) ? Wq16 : Wk16;
    size_t i0 = (size_t)(blk & 1023) * 1024 + tid * 4;
    float4 v = *(const float4*)(src + i0);
    *(uint2*)(dst + i0) = make_uint2(pk2(v.x, v.y), pk2(v.z, v.w));
  } else if (blk < 3200) {
    int lx = tid & 31, ly = tid >> 5;
    if (blk < 3072) {
      int ti = blk - 2048;
      int tx = ti & 31, ty = ti >> 5;
#pragma unroll
      for (int k = 0; k < 4; ++k)
        t[ly + 8 * k][lx] = Wv[(size_t)(ty * 32 + ly + 8 * k) * 1024 + tx * 32 + lx];
      __syncthreads();
#pragma unroll
      for (int k = 0; k < 4; ++k)
        WvT[(size_t)(tx * 32 + ly + 8 * k) * 1024 + ty * 32 + lx] = f2h(t[lx][ly + 8 * k]);
    } else {
      int ti = blk - 3072;
      int tx = ti & 3, ty = ti >> 2;
#pragma unroll
      for (int k = 0; k < 4; ++k)
        t[ly + 8 * k][lx] = Wfc[(size_t)(ty * 32 + ly + 8 * k) * 128 + tx * 32 + lx];
      __syncthreads();
#pragma unroll
      for (int k = 0; k < 4; ++k)
        WfcT[(size_t)(tx * 32 + ly + 8 * k) * 1024 + ty * 32 + lx] = f2h(t[lx][ly + 8 * k]);
    }
  } else {
    int wave = tid >> 6, lane = tid & 63;
    int row = (blk - 3200) * 4 + wave;
    float s = 0.f;
    for (int i = lane; i < 1024; i += 64)
      s += Wk[(size_t)row * 1024 + i] * bq[i];
#pragma unroll
    for (int m = 1; m < 64; m <<= 1) s += __shfl_xor(s, m);
    if (lane == 0) ak[row] = s;
  }
}

__global__ __launch_bounds__(256) void convert4(
    const float* __restrict__ f1, const float* __restrict__ f2,
    const float* __restrict__ f3, const float* __restrict__ f4,
    u16* __restrict__ Zh)
{
  int a = blockIdx.x >> 13;
  const float* f = (a == 0) ? f1 : (a == 1) ? f2 : (a == 2) ? f3 : f4;
  size_t off = (size_t)(blockIdx.x & 8191) * 2048 + threadIdx.x * 8;
  float4 v0 = *(const float4*)(f + off);
  float4 v1 = *(const float4*)(f + off + 4);
  *(uint4*)(Zh + (size_t)a * B_SZ * H_SZ + off) =
      make_uint4(pk2(v0.x, v0.y), pk2(v0.z, v0.w), pk2(v1.x, v1.y), pk2(v1.z, v1.w));
}

// one wave per batch: sum the 16 per-slot partial logits -> 4x4 logits,
// softmax rows, col-sums w_s, g = sum_s w_s z_s
__global__ __launch_bounds__(256) void softmax_g(
    const float* __restrict__ pl, const u16* __restrict__ Zh,
    u16* __restrict__ G)
{
  const size_t FBS = (size_t)B_SZ * H_SZ;
  int wave = threadIdx.x >> 6, lane = threadIdx.x & 63;
  size_t b = (size_t)blockIdx.x * 4 + wave;
  // pl[b][rs][yg16]: lane reads 4 of the 16 slots for rs = lane>>2
  float4 pv = *(const float4*)(pl + b * 256 + (size_t)lane * 4);
  float part = pv.x + pv.y + pv.z + pv.w;
  part += __shfl_xor(part, 1);
  part += __shfl_xor(part, 2);
  // lane group (lane>>2) now holds logit[rs]; broadcast all 16 to every lane
  float l[16];
#pragma unroll
  for (int i = 0; i < 16; ++i) l[i] = __shfl(part, i * 4);
  float w0 = 0, w1 = 0, w2 = 0, w3 = 0;
#pragma unroll
  for (int t = 0; t < 4; ++t) {
    float a0 = l[t * 4], a1 = l[t * 4 + 1], a2 = l[t * 4 + 2], a3 = l[t * 4 + 3];
    float mx = fmaxf(fmaxf(a0, a1), fmaxf(a2, a3));
    float e0 = __expf(a0 - mx), e1 = __expf(a1 - mx), e2 = __expf(a2 - mx), e3 = __expf(a3 - mx);
    float inv = 1.0f / (e0 + e1 + e2 + e3);
    w0 += e0 * inv; w1 += e1 * inv; w2 += e2 * inv; w3 += e3 * inv;
  }
#pragma unroll
  for (int ch = 0; ch < 2; ++ch) {
    size_t h0 = (size_t)lane * 8 + ch * 512;
    float g[8];
#pragma unroll
    for (int j = 0; j < 8; ++j) g[j] = 0.f;
#pragma unroll
    for (int s = 0; s < 4; ++s) {
      float ws = (s == 0) ? w0 : (s == 1) ? w1 : (s == 2) ? w2 : w3;
      uint4 zz = *(const uint4*)(Zh + (size_t)s * FBS + b * H_SZ + h0);
      u32 zs[4] = {zz.x, zz.y, zz.z, zz.w};
#pragma unroll
      for (int j = 0; j < 4; ++j) {
        g[2 * j]     += ws * h2f((u16)(zs[j] & 0xffffu));
        g[2 * j + 1] += ws * h2f((u16)(zs[j] >> 16));
      }
    }
    *(uint4*)(G + b * H_SZ + h0) =
        make_uint4(pk2(g[0], g[1]), pk2(g[2], g[3]), pk2(g[4], g[5]), pk2(g[6], g[7]));
  }
}

// one wave per row: softmax over 128 fc logits
__global__ __launch_bounds__(256) void softmax_out(
    const float* __restrict__ L2, float* __restrict__ out)
{
  int wave = threadIdx.x >> 6, lane = threadIdx.x & 63;
  size_t row = (size_t)blockIdx.x * 4 + wave;
  float2 v = *(const float2*)(L2 + row * 128 + lane * 2);
  float mx = fmaxf(v.x, v.y);
#pragma unroll
  for (int m = 1; m < 64; m <<= 1) mx = fmaxf(mx, __shfl_xor(mx, m));
  float e0 = __expf(v.x - mx), e1 = __expf(v.y - mx);
  float s = e0 + e1;
#pragma unroll
  for (int m = 1; m < 64; m <<= 1) s += __shfl_xor(s, m);
  float inv = 1.0f / s;
  *(float2*)(out + row * 128 + lane * 2) = make_float2(e0 * inv, e1 * inv);
}

extern "C" void kernel_launch(void* const* d_in, const int* in_sizes, int n_in,
                              void* d_out, int out_size, void* d_ws, size_t ws_size,
                              hipStream_t stream)
{
  const float* f1  = (const float*)d_in[0];
  const float* f2  = (const float*)d_in[1];
  const float* f3  = (const float*)d_in[2];
  const float* f4  = (const float*)d_in[3];
  const float* Wq  = (const float*)d_in[4];
  const float* bq  = (const float*)d_in[5];
  const float* Wk  = (const float*)d_in[6];
  // d_in[7] = bk: logit contribution constant over softmax axis -> dropped.
  const float* Wv  = (const float*)d_in[8];
  const float* bv  = (const float*)d_in[9];
  const float* Wfc = (const float*)d_in[10];
  const float* bfc = (const float*)d_in[11];

  float* x_out = (float*)d_out;
  float* out2  = x_out + (size_t)B_SZ * H_SZ;

  const size_t BH = (size_t)B_SZ * H_SZ;
  const size_t HH = (size_t)H_SZ * H_SZ;
  char* w = (char*)d_ws;
  u16* Zh   = (u16*)w;  w += 4 * BH * sizeof(u16);   // 128 MiB fp16 z
  u16* G    = (u16*)w;  w += BH * sizeof(u16);       // 32 MiB
  u16* Xh   = (u16*)w;  w += BH * sizeof(u16);       // 32 MiB
  u16* Wq16 = (u16*)w;  w += HH * 2;
  u16* Wk16 = (u16*)w;  w += HH * 2;
  u16* AT   = (u16*)w;  w += HH * 2;   // AT[i,h] = sum_j Wk[i,j]Wq[h,j]
  u16* WvT  = (u16*)w;  w += HH * 2;   // WvT[n,k] = Wv[k,n]
  u16* WfcT = (u16*)w;  w += (size_t)OUT_SZ * H_SZ * 2;
  float* ak  = (float*)w;  w += H_SZ * sizeof(float);
  float* fcl = (float*)w;  w += (size_t)B_SZ * OUT_SZ * sizeof(float);
  // pl (16 MiB partial logits) overlays the start of Xh: pl is produced by
  // gemm_nt256<1> and fully consumed by softmax_g BEFORE gemm_nt256<2>
  // writes Xh. Keeps total workspace within the previously-passing layout.
  float* pl  = (float*)Xh;

  prep_weights<<<3456, 256, 0, stream>>>(Wq, Wk, Wv, Wfc, bq,
      Wq16, Wk16, WvT, WfcT, ak);
  convert4<<<32768, 256, 0, stream>>>(f1, f2, f3, f4, Zh);
  // AT = Wk @ Wq^T (fp16 out)
  gemm_nt<0><<<dim3(8, 8), 256, 0, stream>>>(
      Wk16, Wq16, 1024, 1024, nullptr, AT, nullptr);
  // R = Z @ AT^T, fused (R+ak)·z epilogue -> partial logits pl[b][ts][yg]
  gemm_nt256<1><<<dim3(256, 4), 512, 0, stream>>>(
      Zh, AT, pl, nullptr, ak, Zh);
  softmax_g<<<4096, 256, 0, stream>>>(pl, Zh, G);
  // x = G @ Wv + 4*bv  (fp32 -> d_out, fp16 -> Xh)
  gemm_nt256<2><<<dim3(64, 4), 512, 0, stream>>>(
      G, WvT, x_out, Xh, bv, nullptr);
  // fc logits = x @ Wfc + bfc
  gemm_nt<3><<<dim3(128, 1), 256, 0, stream>>>(
      Xh, WfcT, 128, 1024, fcl, nullptr, bfc);
  softmax_out<<<4096, 256, 0, stream>>>(fcl, out2);
}